// Round 11
// baseline (206.365 us; speedup 1.0000x reference)
//
#include <hip/hip_runtime.h>
#include <hip/hip_bf16.h>
#include <stdint.h>

// Fused causal attention head, MI355X (gfx950). Round 11.
// attn: 128-row q-tiles; wave = 32 q-rows (2 subtiles) sharing one K/V
// frag read per tile (halves LDS bytes/score). Uniform 4-k-tile chunks,
// 1088 blocks, 4/CU. Partials stored bf16 (lane-pair shfl pack) ->
// opart traffic halved. proj/wprep = R10 (proven).

#define EMBED 384
#define HEAD  64
#define NB    4
#define NT    4096
#define NROWS (NB * NT) // 16384
#define MAXCH 16        // max chunks per 128-row q-tile (m=31 -> 16)

#define SCALE_Q 0.18033688011112042f // 0.125 * log2(e), folded into Q

typedef short bf16x8 __attribute__((ext_vector_type(8)));
typedef float f32x4  __attribute__((ext_vector_type(4)));

__device__ __forceinline__ unsigned short bfround(float f) {
    union { float f; unsigned u; } v; v.f = f;
    return (unsigned short)((v.u + 0x8000u) >> 16);
}
__device__ __forceinline__ unsigned packbf(float lo, float hi) {
    union { float f; unsigned u; } a, b; a.f = lo; b.f = hi;
    return ((a.u + 0x8000u) >> 16) | ((b.u + 0x8000u) & 0xFFFF0000u);
}

// ---------------------------------------------------------------------------
__global__ __launch_bounds__(256)
void wprep_kernel(const float* __restrict__ Wq,
                  const float* __restrict__ Wk,
                  const float* __restrict__ Wv,
                  unsigned short* __restrict__ Wt)
{
    int idx = blockIdx.x * 256 + threadIdx.x;
    int k = idx / 192;
    int n = idx - k * 192;
    int sel = n >> 6, nc = n & 63;
    const float* wp = (sel == 0) ? Wq : ((sel == 1) ? Wk : Wv);
    Wt[n * EMBED + k] = bfround(wp[(size_t)k * HEAD + nc]);
}

// ---------------------------------------------------------------------------
// proj: identical to R10 (256 blocks x 64 rows x 192 cols, full-sector writes).
// ---------------------------------------------------------------------------
__global__ __launch_bounds__(256, 4)
void proj_kernel(const float* __restrict__ x,
                 const unsigned short* __restrict__ Wt,
                 unsigned short* __restrict__ Qo,
                 unsigned short* __restrict__ Ko,
                 unsigned short* __restrict__ Vto)
{
    __shared__ __attribute__((aligned(16))) unsigned short wsm[192][72];
    __shared__ __attribute__((aligned(16))) unsigned short xs[64][72];
    unsigned short (*vbuf)[72] = (unsigned short (*)[72])&xs[0][0];

    const int t    = threadIdx.x;
    const int w    = t >> 6;
    const int lane = t & 63;
    const int quad = lane >> 4;
    const int l16  = lane & 15;
    const int r0   = blockIdx.x * 64;

    f32x4 acc[12];
#pragma unroll
    for (int i = 0; i < 12; ++i) acc[i] = (f32x4){0.f, 0.f, 0.f, 0.f};

    const int wrow = t >> 3, wc = t & 7;
    const int xrow = t >> 4, xc = t & 15;

    for (int kc = 0; kc < 6; ++kc) {
        const int k0 = kc * 64;
        uint4 wr[6];
#pragma unroll
        for (int i = 0; i < 6; ++i)
            wr[i] = *(const uint4*)(Wt + (size_t)(wrow + i * 32) * EMBED + k0 + wc * 8);
        float4 xr[4];
#pragma unroll
        for (int i = 0; i < 4; ++i)
            xr[i] = *(const float4*)(x + (size_t)(r0 + xrow + i * 16) * EMBED + k0 + xc * 4);
        __syncthreads();
#pragma unroll
        for (int i = 0; i < 6; ++i)
            *(uint4*)&wsm[wrow + i * 32][wc * 8] = wr[i];
#pragma unroll
        for (int i = 0; i < 4; ++i) {
            uint2 pw; pw.x = packbf(xr[i].x, xr[i].y); pw.y = packbf(xr[i].z, xr[i].w);
            *(uint2*)&xs[xrow + i * 16][xc * 4] = pw;
        }
        __syncthreads();
#pragma unroll
        for (int ks = 0; ks < 2; ++ks) {
            bf16x8 a = *(const bf16x8*)&xs[w * 16 + l16][ks * 32 + quad * 8];
#pragma unroll
            for (int nt = 0; nt < 12; ++nt) {
                bf16x8 b = *(const bf16x8*)&wsm[nt * 16 + l16][ks * 32 + quad * 8];
                acc[nt] = __builtin_amdgcn_mfma_f32_16x16x32_bf16(a, b, acc[nt], 0, 0, 0);
            }
        }
    }

#pragma unroll
    for (int nt = 0; nt < 8; ++nt) {
        int col = (nt & 3) * 16 + l16;
#pragma unroll
        for (int r = 0; r < 4; ++r) {
            int row = r0 + w * 16 + quad * 4 + r;
            if (nt < 4) Qo[(size_t)row * HEAD + col] = bfround(acc[nt][r] * SCALE_Q);
            else        Ko[(size_t)row * HEAD + col] = bfround(acc[nt][r]);
        }
    }
    __syncthreads();
#pragma unroll
    for (int nt = 8; nt < 12; ++nt) {
        int d = (nt & 3) * 16 + l16;
#pragma unroll
        for (int r = 0; r < 4; ++r)
            vbuf[d][w * 16 + quad * 4 + r] = bfround(acc[nt][r]);
    }
    __syncthreads();
    {
        const int batch = r0 >> 12;
        const int s0 = r0 & (NT - 1);
#pragma unroll
        for (int i = 0; i < 2; ++i) {
            int idx = t + i * 256;
            int d = idx >> 3, c = idx & 7;
            *(uint4*)(Vto + ((size_t)(batch * HEAD + d)) * NT + s0 + c * 8) =
                *(const uint4*)&vbuf[d][c * 8];
        }
    }
}

// ---------------------------------------------------------------------------
// attn: 1088 blocks x 256 thr. batch = blk&3; bid = blk>>2 decodes to
// (m, c) over m=31..0 with nchunks(m) = (m+2)>>1 (descending-m = LPT).
// Block = 128 q-rows (q-tile m); wave w owns rows [m*128+w*32, +32) as two
// 16-row subtiles sharing one K/V frag read per 64-key tile. Chunk c covers
// k-tiles [4c, min(4c+4, 2m+2)). K/V staged to LDS with XOR-chunk swizzle;
// next tile prefetched into regs. Partials: bf16 o-plane (shfl pair-pack,
// full 128B row sectors) + f32 l, keyed by chunk c.
// ---------------------------------------------------------------------------
__global__ __launch_bounds__(256, 4)
void attn_kernel(const unsigned short* __restrict__ Qi,
                 const unsigned short* __restrict__ Ki,
                 const unsigned short* __restrict__ Vti,
                 unsigned short* __restrict__ opart,
                 float* __restrict__ lpart)
{
    __shared__ __attribute__((aligned(16))) unsigned short Kt[64][64];
    __shared__ __attribute__((aligned(16))) unsigned short Vs[64][64];
    __shared__ __attribute__((aligned(16))) unsigned short Ps[4][16][72];

    const int t    = threadIdx.x;
    const int w    = t >> 6;
    const int lane = t & 63;
    const int quad = lane >> 4;
    const int l16  = lane & 15;
    const int sw   = l16 & 7;

    const int batch = blockIdx.x & 3;
    int bid = blockIdx.x >> 2; // 0..271, descending-m (big work first)
    int m = 31;
    int nch = 16; // (31+2)>>1
    while (bid >= nch) { bid -= nch; --m; nch = (m + 2) >> 1; }
    const int c = bid;
    const int kt0 = c * 4;
    const int ntiles = min(4, 2 * m + 2 - kt0); // 1..4
    const int qw = m * 128 + w * 32;            // wave q base (within batch)

    const unsigned short* Kbg = Ki  + (size_t)batch * NT * HEAD;
    const unsigned short* Vbg = Vti + (size_t)batch * HEAD * NT;

    // Q B-frags, 2 subtiles (Q carries 0.125*log2e)
    bf16x8 bq0[2], bq1[2];
#pragma unroll
    for (int qs = 0; qs < 2; ++qs) {
        const unsigned short* qp = Qi + (size_t)(batch * NT + qw + qs * 16 + l16) * HEAD + quad * 8;
        bq0[qs] = *(const bf16x8*)(qp);
        bq1[qs] = *(const bf16x8*)(qp + 32);
    }

    f32x4 o[2][4];
#pragma unroll
    for (int a = 0; a < 2; ++a)
#pragma unroll
        for (int b = 0; b < 4; ++b) o[a][b] = (f32x4){0.f, 0.f, 0.f, 0.f};
    float rs[2] = {0.f, 0.f};

    const int srow0 = t >> 3, sc = t & 7;
    const int srow1 = srow0 + 32;
    const int scc0 = sc ^ (srow0 & 7);
    const int scc1 = sc ^ (srow1 & 7);

    uint4 kr0, kr1, vr0, vr1;
    kr0 = *(const uint4*)(Kbg + (size_t)(kt0 * 64 + srow0) * HEAD + sc * 8);
    kr1 = *(const uint4*)(Kbg + (size_t)(kt0 * 64 + srow1) * HEAD + sc * 8);
    vr0 = *(const uint4*)(Vbg + (size_t)srow0 * NT + kt0 * 64 + sc * 8);
    vr1 = *(const uint4*)(Vbg + (size_t)srow1 * NT + kt0 * 64 + sc * 8);

    for (int j = 0; j < ntiles; ++j) {
        const int kt = kt0 + j;
        __syncthreads(); // previous tile's frag reads complete
        *(uint4*)&Kt[srow0][scc0 * 8] = kr0;
        *(uint4*)&Kt[srow1][scc1 * 8] = kr1;
        *(uint4*)&Vs[srow0][scc0 * 8] = vr0;
        *(uint4*)&Vs[srow1][scc1 * 8] = vr1;
        __syncthreads(); // tile visible
        if (j + 1 < ntiles) {
            const int nt4 = (kt + 1) * 64;
            kr0 = *(const uint4*)(Kbg + (size_t)(nt4 + srow0) * HEAD + sc * 8);
            kr1 = *(const uint4*)(Kbg + (size_t)(nt4 + srow1) * HEAD + sc * 8);
            vr0 = *(const uint4*)(Vbg + (size_t)srow0 * NT + nt4 + sc * 8);
            vr1 = *(const uint4*)(Vbg + (size_t)srow1 * NT + nt4 + sc * 8);
        }

        // K and V frags loaded ONCE, shared by both q-subtiles
        bf16x8 ak0[4], ak1[4], av0[4], av1[4];
#pragma unroll
        for (int ts = 0; ts < 4; ++ts) {
            ak0[ts] = *(const bf16x8*)&Kt[ts * 16 + l16][(quad ^ sw) * 8];
            ak1[ts] = *(const bf16x8*)&Kt[ts * 16 + l16][((4 + quad) ^ sw) * 8];
        }
#pragma unroll
        for (int nd = 0; nd < 4; ++nd) {
            av0[nd] = *(const bf16x8*)&Vs[nd * 16 + l16][(quad ^ sw) * 8];
            av1[nd] = *(const bf16x8*)&Vs[nd * 16 + l16][((4 + quad) ^ sw) * 8];
        }

        const bool diag = (kt >= 2 * m); // only the last 1-2 tiles can mask
#pragma unroll
        for (int qs = 0; qs < 2; ++qs) {
            f32x4 z[4];
#pragma unroll
            for (int ts = 0; ts < 4; ++ts) {
                f32x4 zz = (f32x4){0.f, 0.f, 0.f, 0.f};
                zz = __builtin_amdgcn_mfma_f32_16x16x32_bf16(ak0[ts], bq0[qs], zz, 0, 0, 0);
                zz = __builtin_amdgcn_mfma_f32_16x16x32_bf16(ak1[ts], bq1[qs], zz, 0, 0, 0);
                z[ts] = zz;
            }
            const int qg = qw + qs * 16 + l16; // this lane's q row
#pragma unroll
            for (int ts = 0; ts < 4; ++ts) {
                float p[4];
#pragma unroll
                for (int r = 0; r < 4; ++r) {
                    float pv = __builtin_amdgcn_exp2f(z[ts][r]);
                    if (diag) {
                        int sg = kt * 64 + ts * 16 + quad * 4 + r;
                        pv = (sg > qg) ? 0.f : pv;
                    }
                    p[r] = pv;
                }
                rs[qs] += (p[0] + p[1]) + (p[2] + p[3]);
                uint2 pw; pw.x = packbf(p[0], p[1]); pw.y = packbf(p[2], p[3]);
                *(uint2*)&Ps[w][l16][ts * 16 + quad * 4] = pw;
            }
            bf16x8 ap0 = *(const bf16x8*)&Ps[w][l16][quad * 8];
            bf16x8 ap1 = *(const bf16x8*)&Ps[w][l16][32 + quad * 8];
#pragma unroll
            for (int nd = 0; nd < 4; ++nd) {
                o[qs][nd] = __builtin_amdgcn_mfma_f32_16x16x32_bf16(ap0, av0[nd], o[qs][nd], 0, 0, 0);
                o[qs][nd] = __builtin_amdgcn_mfma_f32_16x16x32_bf16(ap1, av1[nd], o[qs][nd], 0, 0, 0);
            }
        }
    }

    // epilogue: l partials + bf16 o partials (lane-pair pack, even lane stores)
#pragma unroll
    for (int qs = 0; qs < 2; ++qs) {
        float vs = rs[qs];
        vs += __shfl_xor(vs, 16, 64);
        vs += __shfl_xor(vs, 32, 64);
        if (quad == 0)
            lpart[(size_t)c * NROWS + batch * NT + qw + qs * 16 + l16] = vs;
    }
    unsigned short* ob = opart + (size_t)c * NROWS * HEAD + (size_t)batch * NT * HEAD;
#pragma unroll
    for (int qs = 0; qs < 2; ++qs)
#pragma unroll
        for (int nd = 0; nd < 4; ++nd)
#pragma unroll
            for (int r = 0; r < 4; ++r) {
                float own = o[qs][nd][r];
                float oth = __shfl_xor(own, 1, 64);
                unsigned u = (lane & 1) ? packbf(oth, own) : packbf(own, oth);
                if (!(lane & 1)) {
                    int row = qw + qs * 16 + quad * 4 + r;
                    *(unsigned*)&ob[(size_t)row * HEAD + nd * 16 + l16] = u;
                }
            }
}

// ---------------------------------------------------------------------------
// combine: per-row chunk count = (m+2)>>1, m = (row%NT)>>7. bf16 planes.
// Thread handles 8 cols: gid over NROWS*8.
// ---------------------------------------------------------------------------
__global__ __launch_bounds__(256)
void combine_kernel(const unsigned short* __restrict__ opart,
                    const float* __restrict__ lpart,
                    float* __restrict__ out)
{
    int gid = blockIdx.x * 256 + threadIdx.x;
    int row = gid >> 3;
    int d8  = (gid & 7) * 8;
    int m   = (row & (NT - 1)) >> 7;
    int nch = (m + 2) >> 1;
    float acc[8] = {0.f, 0.f, 0.f, 0.f, 0.f, 0.f, 0.f, 0.f};
    float l = 0.f;
    for (int cc = 0; cc < nch; ++cc) {
        const unsigned short* p = opart + (size_t)cc * NROWS * HEAD + (size_t)row * HEAD + d8;
        uint4 u = *(const uint4*)p;
        union { unsigned u; float f; } cv;
#pragma unroll
        for (int i = 0; i < 4; ++i) {
            unsigned ui = (i == 0) ? u.x : (i == 1) ? u.y : (i == 2) ? u.z : u.w;
            cv.u = ui << 16;          acc[i * 2]     += cv.f;
            cv.u = ui & 0xFFFF0000u;  acc[i * 2 + 1] += cv.f;
        }
        l += lpart[(size_t)cc * NROWS + row];
    }
    float inv = 1.0f / l;
    float4 r0, r1;
    r0.x = acc[0] * inv; r0.y = acc[1] * inv; r0.z = acc[2] * inv; r0.w = acc[3] * inv;
    r1.x = acc[4] * inv; r1.y = acc[5] * inv; r1.z = acc[6] * inv; r1.w = acc[7] * inv;
    *(float4*)(out + (size_t)row * HEAD + d8)     = r0;
    *(float4*)(out + (size_t)row * HEAD + d8 + 4) = r1;
}

extern "C" void kernel_launch(void* const* d_in, const int* in_sizes, int n_in,
                              void* d_out, int out_size, void* d_ws, size_t ws_size,
                              hipStream_t stream)
{
    const float* x  = (const float*)d_in[0];
    const float* Wq = (const float*)d_in[1];
    const float* Wk = (const float*)d_in[2];
    const float* Wv = (const float*)d_in[3];
    float* out = (float*)d_out;

    // ws: Q | K | V^T (2MB each bf16) | W^T (144KB) | opart bf16 (32MB) | lpart (1MB)
    unsigned short* Qw  = (unsigned short*)d_ws;
    unsigned short* Kw  = Qw + (size_t)NROWS * HEAD;
    unsigned short* Vtw = Kw + (size_t)NROWS * HEAD;
    unsigned short* Wtw = Vtw + (size_t)NROWS * HEAD;
    unsigned short* opart = Wtw + (size_t)192 * EMBED;
    float* lpart = (float*)(opart + (size_t)MAXCH * NROWS * HEAD);

    wprep_kernel<<<(192 * EMBED) / 256, 256, 0, stream>>>(Wq, Wk, Wv, Wtw);
    proj_kernel<<<NROWS / 64, 256, 0, stream>>>(x, Wtw, Qw, Kw, Vtw);
    attn_kernel<<<4 * 272, 256, 0, stream>>>(Qw, Kw, Vtw, opart, lpart);
    combine_kernel<<<NROWS * 8 / 256, 256, 0, stream>>>(opart, lpart, out);
}